// Round 22
// baseline (174.548 us; speedup 1.0000x reference)
//
#include <hip/hip_runtime.h>
#include <hip/hip_bf16.h>

#define N_NODES 50000
#define N_EDGES 800000
#define HID 128

using short8  = __attribute__((ext_vector_type(8))) short;
using floatx4 = __attribute__((ext_vector_type(4))) float;

__device__ __forceinline__ float bf2f(ushort u) {
    union { uint u32; float f; } v; v.u32 = ((uint)u) << 16; return v.f;
}
__device__ __forceinline__ ushort f2bf(float f) {
    __hip_bfloat16 b = __float2bfloat16(f);
    return *reinterpret_cast<ushort*>(&b);
}

// packed-bf16 atomic add via CAS (boundary runs only; few contenders/addr)
__device__ __forceinline__ void atomicAddBf162(uint* addr, float a0, float a1) {
    uint old = *addr;
    while (true) {
        float s0 = bf2f((ushort)(old & 0xffffu)) + a0;
        float s1 = bf2f((ushort)(old >> 16)) + a1;
        uint newv = (uint)f2bf(s0) | ((uint)f2bf(s1) << 16);
        uint got = atomicCAS(addr, old, newv);
        if (got == old) break;
        old = got;
    }
}

// ---- hist (slot-returning) + prep (weight transposes), fused by gid range ----
__global__ __launch_bounds__(256) void prep_hist_kernel(
    const float* __restrict__ mw1, const float* __restrict__ mb1,
    const float* __restrict__ mw2,
    const float* __restrict__ uw1, const float* __restrict__ uw2,
    const float* __restrict__ dec_w,
    ushort* __restrict__ w1at, ushort* __restrict__ w1bt,
    ushort* __restrict__ w2t,
    ushort* __restrict__ uw1t, ushort* __restrict__ uw2t,
    ushort* __restrict__ dec_wt,
    float4* __restrict__ tailpack,
    const int* __restrict__ ei, uint* __restrict__ counts,
    uint* __restrict__ slot)
{
    int gid = blockIdx.x * 256 + threadIdx.x;
    if (gid < N_EDGES) {
        slot[gid] = atomicAdd(&counts[ei[N_EDGES + gid]], 1u);
        return;
    }
    int g0 = gid - N_EDGES;
    if (g0 < 16384) {
        int c = g0 >> 7, k = g0 & 127;
        w1at[c * 128 + k] = f2bf(mw1[(size_t)k * HID + c]);
    } else if (g0 < 32768) {
        int g = g0 - 16384, c = g >> 7, k = g & 127;
        w1bt[c * 128 + k] = f2bf(mw1[(size_t)(128 + k) * HID + c]);
    } else if (g0 < 49152) {
        int g = g0 - 32768, c = g >> 7, k = g & 127;
        w2t[c * 128 + k] = f2bf(mw2[(size_t)k * HID + c]);
    } else if (g0 < 81920) {
        int g = g0 - 49152, c = g >> 8, k = g & 255;
        uw1t[c * 256 + k] = f2bf(uw1[(size_t)k * HID + c]);
    } else if (g0 < 98304) {
        int g = g0 - 81920, c = g >> 7, k = g & 127;
        uw2t[c * 128 + k] = f2bf(uw2[(size_t)k * HID + c]);
    } else if (g0 < 98432) {
        int c = g0 - 98304;
        tailpack[c] = make_float4(mw1[(size_t)256 * HID + c],
                                  mw1[(size_t)257 * HID + c],
                                  mw1[(size_t)258 * HID + c],
                                  mb1[c]);
    } else if (g0 < 100480) {
        int g = g0 - 98432, c = g >> 7, k = g & 127;    // dec_wt [16][128], pad 0
        dec_wt[c * 128 + k] = (c < 5) ? f2bf(dec_w[(size_t)k * 5 + c]) : (ushort)0;
    }
}

// ---- mega: pre + Tb zero (bf16) + scan1, fused by block range ---------------
#define SCAN1_B 98
#define ZERO_B  1563
#define PRE_B   782
#define SCAN_B  196
__global__ __launch_bounds__(512, 2) void mega_kernel(
    const uint* __restrict__ counts, uint* __restrict__ partials,
    uint4* __restrict__ Tb4,
    const float* __restrict__ x, const float* __restrict__ enc_w,
    const float* __restrict__ enc_b,
    const ushort* __restrict__ w1at, const ushort* __restrict__ w1bt,
    ushort* __restrict__ hb, ushort* __restrict__ Abuf, ushort* __restrict__ Bbuf)
{
    __shared__ __align__(16) ushort htile[64][152];
    __shared__ __align__(16) ushort ABst[64][280];
    __shared__ float x_s[64][6];
    __shared__ float encw_s[640];
    __shared__ float encb_s[128];
    __shared__ uint sm[512];

    int tid = threadIdx.x;
    int b = blockIdx.x;

    if (b >= PRE_B) {
        if (b < PRE_B + ZERO_B) {
            int idx = (b - PRE_B) * 512 + tid;
            if (idx < 800000) Tb4[idx] = make_uint4(0, 0, 0, 0);
        } else {
            int bs = b - PRE_B - ZERO_B;   // scan1: two 256-partials per block
            int i = bs * 512 + tid;
            sm[tid] = (i < N_NODES) ? counts[i] : 0u;
            __syncthreads();
            int half = tid >> 8, t = tid & 255;
            for (int off = 128; off > 0; off >>= 1) {
                if (t < off) sm[half * 256 + t] += sm[half * 256 + t + off];
                __syncthreads();
            }
            if (t == 0) partials[2 * bs + half] = sm[half * 256];
        }
        return;
    }

    // ---- pre path ----
    int n0 = b * 64;

    if (tid < 320) {
        int nl = tid / 5, k = tid % 5;
        int n = n0 + nl;
        x_s[nl][k] = (n < N_NODES) ? x[(size_t)n * 5 + k] : 0.f;
    }
    if (tid < 128) encb_s[tid] = enc_b[tid];
    encw_s[tid] = enc_w[tid];
    if (tid < 128) encw_s[512 + tid] = enc_w[512 + tid];
    __syncthreads();

    {
        int el = tid >> 3, q = tid & 7;
        int c0 = q * 16;
        union { ushort u[16]; uint4 v[2]; } hv;
#pragma unroll
        for (int c = 0; c < 16; ++c) {
            int j = c0 + c;
            float acc = encb_s[j];
#pragma unroll
            for (int k = 0; k < 5; ++k)
                acc = fmaf(x_s[el][k], encw_s[k * 128 + j], acc);
            hv.u[c] = f2bf(acc);
        }
        *(uint4*)&htile[el][c0]     = hv.v[0];
        *(uint4*)&htile[el][c0 + 8] = hv.v[1];
        int n = n0 + el;
        if (n < N_NODES) {
            uint4* gp = (uint4*)(hb + (size_t)n * HID + c0);
            gp[0] = hv.v[0];
            gp[1] = hv.v[1];
        }
    }
    __syncthreads();

    int lane = tid & 63;
    int wid  = tid >> 6;
    int cg   = wid & 3;
    int mg   = wid >> 2;
    int lhi  = lane >> 4;
    int llo  = lane & 15;
    int col0 = cg * 32 + llo;
    int col1 = cg * 32 + 16 + llo;

    {
        floatx4 acc[2][2];
#pragma unroll
        for (int lm = 0; lm < 2; ++lm)
#pragma unroll
            for (int r = 0; r < 4; ++r) { acc[lm][0][r] = 0.f; acc[lm][1][r] = 0.f; }
        const ushort* bp0 = w1at + (size_t)col0 * 128 + lhi * 8;
        const ushort* bp1 = w1at + (size_t)col1 * 128 + lhi * 8;
#pragma unroll
        for (int kk = 0; kk < 4; ++kk) {
            short8 bf0 = *(const short8*)(bp0 + kk * 32);
            short8 bf1 = *(const short8*)(bp1 + kk * 32);
#pragma unroll
            for (int lm = 0; lm < 2; ++lm) {
                int row = (mg * 2 + lm) * 16 + llo;
                short8 a = *(const short8*)((const char*)htile + (size_t)row * 304 + kk * 64 + lhi * 16);
                acc[lm][0] = __builtin_amdgcn_mfma_f32_16x16x32_bf16(a, bf0, acc[lm][0], 0, 0, 0);
                acc[lm][1] = __builtin_amdgcn_mfma_f32_16x16x32_bf16(a, bf1, acc[lm][1], 0, 0, 0);
            }
        }
#pragma unroll
        for (int lm = 0; lm < 2; ++lm)
#pragma unroll
            for (int r = 0; r < 4; ++r) {
                int row = (mg * 2 + lm) * 16 + lhi * 4 + r;
                ABst[row][col0] = f2bf(acc[lm][0][r]);
                ABst[row][col1] = f2bf(acc[lm][1][r]);
            }
    }
    {
        floatx4 acc[2][2];
#pragma unroll
        for (int lm = 0; lm < 2; ++lm)
#pragma unroll
            for (int r = 0; r < 4; ++r) { acc[lm][0][r] = 0.f; acc[lm][1][r] = 0.f; }
        const ushort* bp0 = w1bt + (size_t)col0 * 128 + lhi * 8;
        const ushort* bp1 = w1bt + (size_t)col1 * 128 + lhi * 8;
#pragma unroll
        for (int kk = 0; kk < 4; ++kk) {
            short8 bf0 = *(const short8*)(bp0 + kk * 32);
            short8 bf1 = *(const short8*)(bp1 + kk * 32);
#pragma unroll
            for (int lm = 0; lm < 2; ++lm) {
                int row = (mg * 2 + lm) * 16 + llo;
                short8 a = *(const short8*)((const char*)htile + (size_t)row * 304 + kk * 64 + lhi * 16);
                acc[lm][0] = __builtin_amdgcn_mfma_f32_16x16x32_bf16(a, bf0, acc[lm][0], 0, 0, 0);
                acc[lm][1] = __builtin_amdgcn_mfma_f32_16x16x32_bf16(a, bf1, acc[lm][1], 0, 0, 0);
            }
        }
#pragma unroll
        for (int lm = 0; lm < 2; ++lm)
#pragma unroll
            for (int r = 0; r < 4; ++r) {
                int row = (mg * 2 + lm) * 16 + lhi * 4 + r;
                ABst[row][128 + col0] = f2bf(acc[lm][0][r]);
                ABst[row][128 + col1] = f2bf(acc[lm][1][r]);
            }
    }
    __syncthreads();

    {
        int el = tid >> 3, q = tid & 7;
        int n = n0 + el;
        if (n < N_NODES) {
            uint4* ga = (uint4*)(Abuf + (size_t)n * HID + q * 16);
            ga[0] = *(uint4*)&ABst[el][q * 16];
            ga[1] = *(uint4*)&ABst[el][q * 16 + 8];
            uint4* gb = (uint4*)(Bbuf + (size_t)n * HID + q * 16);
            gb[0] = *(uint4*)&ABst[el][128 + q * 16];
            gb[1] = *(uint4*)&ABst[el][128 + q * 16 + 8];
        }
    }
}

// scan of partials folded in: every block scans the 196 partials locally.
__global__ __launch_bounds__(256) void scan3_kernel(
    const uint* __restrict__ counts, const uint* __restrict__ partials,
    uint* __restrict__ rowptr)
{
    __shared__ uint sp[256];
    __shared__ uint sm[256];
    __shared__ uint base_s;
    int b = blockIdx.x, tid = threadIdx.x;
    uint pv = (tid < SCAN_B) ? partials[tid] : 0u;
    sp[tid] = pv;
    __syncthreads();
    for (int off = 1; off < 256; off <<= 1) {
        uint t = (tid >= off) ? sp[tid - off] : 0u;
        __syncthreads();
        sp[tid] += t;
        __syncthreads();
    }
    if (tid == (uint)b) base_s = sp[tid] - pv;   // exclusive prefix for this block
    int i = b * 256 + tid;
    uint v = (i < N_NODES) ? counts[i] : 0u;
    sm[tid] = v;
    __syncthreads();
    for (int off = 1; off < 256; off <<= 1) {
        uint t = (tid >= off) ? sm[tid - off] : 0u;
        __syncthreads();
        sm[tid] += t;
        __syncthreads();
    }
    if (i < N_NODES) rowptr[i] = sm[tid] - v + base_s;
    if (i == N_NODES - 1) rowptr[N_NODES] = N_EDGES;
}

// ---- build: scatter packed payload using precomputed slot (no atomics) ------
__global__ __launch_bounds__(256) void build_kernel(
    const int* __restrict__ ei, const float* __restrict__ ea,
    const uint* __restrict__ rowptr, const uint* __restrict__ slot,
    uint4* __restrict__ epack)
{
    int e = blockIdx.x * 256 + threadIdx.x;
    if (e >= N_EDGES) return;
    int src = ei[e];
    int dst = ei[N_EDGES + e];
    uint pos = rowptr[dst] + slot[e];
    uint4 p;
    p.x = (uint)src;
    p.y = (uint)dst;
    p.z = (uint)f2bf(ea[(size_t)e * 3 + 0]) | ((uint)f2bf(ea[(size_t)e * 3 + 1]) << 16);
    p.w = (uint)f2bf(ea[(size_t)e * 3 + 2]);
    epack[pos] = p;
}

// ---- edge: software-pipelined depth-2 + per-run base fold;
//      per-wave 20-edge window (2x TLP); cols {2*lane, 2*lane+1};
//      interior runs -> uint (bf16x2) store; boundaries -> CAS pk-bf16 add ----
#define EPB 160
#define EPW 20
__global__ __launch_bounds__(512) void edge_kernel(
    const ushort* __restrict__ Abuf, const ushort* __restrict__ Bbuf,
    const uint4* __restrict__ epack, const float4* __restrict__ tailpack,
    ushort* __restrict__ Tb)
{
    __shared__ __align__(16) uint4 ep_s[EPB];

    int tid = threadIdx.x;
    size_t p0 = (size_t)blockIdx.x * EPB;
    if (tid < EPB) ep_s[tid] = epack[p0 + tid];
    __syncthreads();

    int wid = tid >> 6, lane = tid & 63;
    int base = wid * EPW;
    float4 tp0 = tailpack[2 * lane];
    float4 tp1 = tailpack[2 * lane + 1];

    // pipeline prologue: payloads j=0,1 and their B-rows in flight
    uint4 pc = ep_s[base];
    uint4 pn = ep_s[base + 1];
    uint buc = ((const uint*)(Bbuf + (size_t)pc.x * HID))[lane];
    uint bun = ((const uint*)(Bbuf + (size_t)pn.x * HID))[lane];

    int prev = (int)pc.y;
    uint au = ((const uint*)(Abuf + (size_t)prev * HID))[lane];
    float base0 = tp0.w + bf2f((ushort)(au & 0xffffu));
    float base1 = tp1.w + bf2f((ushort)(au >> 16));
    float acc0 = 0.f, acc1 = 0.f;
    bool first = true;

#pragma unroll 4
    for (int j = 0; j < EPW; ++j) {
        uint4 p = pc;
        uint bu = buc;
        // advance pipeline: issue load for j+2 before any compute
        pc = pn;
        buc = bun;
        if (j + 2 < EPW) {
            pn = ep_s[base + j + 2];
            bun = ((const uint*)(Bbuf + (size_t)pn.x * HID))[lane];
        }
        int d = (int)p.y;
        if (d != prev) {                    // wave-uniform branch
            uint* Tr = (uint*)(Tb + (size_t)prev * HID) + lane;
            if (first) {
                atomicAddBf162(Tr, acc0, acc1);
            } else {
                *Tr = (uint)f2bf(acc0) | ((uint)f2bf(acc1) << 16);  // interior
            }
            first = false;
            acc0 = 0.f; acc1 = 0.f;
            prev = d;
            au = ((const uint*)(Abuf + (size_t)d * HID))[lane];
            base0 = tp0.w + bf2f((ushort)(au & 0xffffu));
            base1 = tp1.w + bf2f((ushort)(au >> 16));
        }
        float e0 = bf2f((ushort)(p.z & 0xffffu));
        float e1 = bf2f((ushort)(p.z >> 16));
        float e2 = bf2f((ushort)(p.w & 0xffffu));
        float t0 = fmaf(e0, tp0.x, fmaf(e1, tp0.y, fmaf(e2, tp0.z, base0)))
                   + bf2f((ushort)(bu & 0xffffu));
        float t1 = fmaf(e0, tp1.x, fmaf(e1, tp1.y, fmaf(e2, tp1.z, base1)))
                   + bf2f((ushort)(bu >> 16));
        acc0 += fmaxf(t0, 0.f);
        acc1 += fmaxf(t1, 0.f);
    }
    uint* Tr = (uint*)(Tb + (size_t)prev * HID) + lane;   // last run: boundary
    atomicAddBf162(Tr, acc0, acc1);
}

// ---- upd: aggr = Tb@W2 + deg*b2; node MLP + residual + MFMA decode.
__global__ __launch_bounds__(512, 6) void upd_kernel(
    const ushort* __restrict__ hb, const ushort* __restrict__ Tb,
    const uint* __restrict__ rowptr,
    const ushort* __restrict__ w2t, const float* __restrict__ mb2,
    const float* __restrict__ ub1, const float* __restrict__ ub2,
    const ushort* __restrict__ uw1t, const ushort* __restrict__ uw2t,
    const ushort* __restrict__ dec_wt, const float* __restrict__ dec_b,
    float* __restrict__ out)
{
    __shared__ __align__(16) ushort comb[64][280];   // [h | aggr] -> [hf | aggr]
    __shared__ __align__(16) ushort Tt[64][136];     // T bf16 -> t1, pitch 272B
    __shared__ float deg_s[64];

    int tid = threadIdx.x;
    int n0 = blockIdx.x * 64;

    {
        int el = tid >> 3, q = tid & 7;
        int n = n0 + el;
        if (n < N_NODES) {
            const uint4* gp = (const uint4*)(hb + (size_t)n * HID + q * 16);
            uint4* lp = (uint4*)&comb[el][q * 16];
            lp[0] = gp[0]; lp[1] = gp[1];
            const uint4* tp4 = (const uint4*)(Tb + (size_t)n * HID + q * 16);
            *(uint4*)&Tt[el][q * 16]     = tp4[0];
            *(uint4*)&Tt[el][q * 16 + 8] = tp4[1];
        } else {
            uint4 z = make_uint4(0, 0, 0, 0);
            uint4* lp = (uint4*)&comb[el][q * 16];
            lp[0] = z; lp[1] = z;
            *(uint4*)&Tt[el][q * 16]     = z;
            *(uint4*)&Tt[el][q * 16 + 8] = z;
        }
        if (tid < 64) {
            int n2 = n0 + tid;
            deg_s[tid] = (n2 < N_NODES) ? (float)(rowptr[n2 + 1] - rowptr[n2]) : 0.f;
        }
    }
    __syncthreads();

    int lane = tid & 63;
    int wid  = tid >> 6;
    int cg   = wid & 3;
    int mg   = wid >> 2;
    int lhi  = lane >> 4;
    int llo  = lane & 15;
    int col0 = cg * 32 + llo;
    int col1 = cg * 32 + 16 + llo;

    // ---- aggr = Tt @ W2 + deg*b2 -> comb[.,128:256] ----
    {
        floatx4 acc[2][2];
        float b0 = mb2[col0], b1 = mb2[col1];
#pragma unroll
        for (int lm = 0; lm < 2; ++lm)
#pragma unroll
            for (int r = 0; r < 4; ++r) {
                int row = (mg * 2 + lm) * 16 + lhi * 4 + r;
                acc[lm][0][r] = deg_s[row] * b0;
                acc[lm][1][r] = deg_s[row] * b1;
            }
        const ushort* bp0 = w2t + (size_t)col0 * 128 + lhi * 8;
        const ushort* bp1 = w2t + (size_t)col1 * 128 + lhi * 8;
#pragma unroll
        for (int kk = 0; kk < 4; ++kk) {
            short8 bf0 = *(const short8*)(bp0 + kk * 32);
            short8 bf1 = *(const short8*)(bp1 + kk * 32);
#pragma unroll
            for (int lm = 0; lm < 2; ++lm) {
                int row = (mg * 2 + lm) * 16 + llo;
                short8 a = *(const short8*)((const char*)Tt + (size_t)row * 272 + kk * 64 + lhi * 16);
                acc[lm][0] = __builtin_amdgcn_mfma_f32_16x16x32_bf16(a, bf0, acc[lm][0], 0, 0, 0);
                acc[lm][1] = __builtin_amdgcn_mfma_f32_16x16x32_bf16(a, bf1, acc[lm][1], 0, 0, 0);
            }
        }
#pragma unroll
        for (int lm = 0; lm < 2; ++lm)
#pragma unroll
            for (int r = 0; r < 4; ++r) {
                int row = (mg * 2 + lm) * 16 + lhi * 4 + r;
                comb[row][128 + col0] = f2bf(acc[lm][0][r]);
                comb[row][128 + col1] = f2bf(acc[lm][1][r]);
            }
    }
    __syncthreads();

    // ---- layer 1: comb @ uw1 + ub1, relu -> Tt (T data now dead) ----
    {
        floatx4 acc[2][2];
        float b0 = ub1[col0], b1 = ub1[col1];
#pragma unroll
        for (int lm = 0; lm < 2; ++lm)
#pragma unroll
            for (int r = 0; r < 4; ++r) { acc[lm][0][r] = b0; acc[lm][1][r] = b1; }
        const ushort* bp0 = uw1t + (size_t)col0 * 256 + lhi * 8;
        const ushort* bp1 = uw1t + (size_t)col1 * 256 + lhi * 8;
#pragma unroll
        for (int kk = 0; kk < 8; ++kk) {
            short8 bf0 = *(const short8*)(bp0 + kk * 32);
            short8 bf1 = *(const short8*)(bp1 + kk * 32);
#pragma unroll
            for (int lm = 0; lm < 2; ++lm) {
                int row = (mg * 2 + lm) * 16 + llo;
                short8 a = *(const short8*)((const char*)comb + (size_t)row * 560 + kk * 64 + lhi * 16);
                acc[lm][0] = __builtin_amdgcn_mfma_f32_16x16x32_bf16(a, bf0, acc[lm][0], 0, 0, 0);
                acc[lm][1] = __builtin_amdgcn_mfma_f32_16x16x32_bf16(a, bf1, acc[lm][1], 0, 0, 0);
            }
        }
        __syncthreads();
#pragma unroll
        for (int lm = 0; lm < 2; ++lm)
#pragma unroll
            for (int r = 0; r < 4; ++r) {
                int row = (mg * 2 + lm) * 16 + lhi * 4 + r;
                Tt[row][col0] = f2bf(fmaxf(acc[lm][0][r], 0.f));
                Tt[row][col1] = f2bf(fmaxf(acc[lm][1][r], 0.f));
            }
    }
    __syncthreads();

    // ---- layer 2 + residual -> comb[.,0:128] (hf over h, same-thread elements) -
    {
        floatx4 acc[2][2];
        float b0 = ub2[col0], b1 = ub2[col1];
#pragma unroll
        for (int lm = 0; lm < 2; ++lm)
#pragma unroll
            for (int r = 0; r < 4; ++r) { acc[lm][0][r] = b0; acc[lm][1][r] = b1; }
        const ushort* bp0 = uw2t + (size_t)col0 * 128 + lhi * 8;
        const ushort* bp1 = uw2t + (size_t)col1 * 128 + lhi * 8;
#pragma unroll
        for (int kk = 0; kk < 4; ++kk) {
            short8 bf0 = *(const short8*)(bp0 + kk * 32);
            short8 bf1 = *(const short8*)(bp1 + kk * 32);
#pragma unroll
            for (int lm = 0; lm < 2; ++lm) {
                int row = (mg * 2 + lm) * 16 + llo;
                short8 a = *(const short8*)((const char*)Tt + (size_t)row * 272 + kk * 64 + lhi * 16);
                acc[lm][0] = __builtin_amdgcn_mfma_f32_16x16x32_bf16(a, bf0, acc[lm][0], 0, 0, 0);
                acc[lm][1] = __builtin_amdgcn_mfma_f32_16x16x32_bf16(a, bf1, acc[lm][1], 0, 0, 0);
            }
        }
#pragma unroll
        for (int lm = 0; lm < 2; ++lm)
#pragma unroll
            for (int r = 0; r < 4; ++r) {
                int row = (mg * 2 + lm) * 16 + lhi * 4 + r;
                float h0 = bf2f(comb[row][col0]);
                float h1 = bf2f(comb[row][col1]);
                comb[row][col0] = f2bf(h0 + acc[lm][0][r]);
                comb[row][col1] = f2bf(h1 + acc[lm][1][r]);
            }
    }
    __syncthreads();

    // ---- decode via MFMA: [64,128] @ [128,16(pad)] ; waves 0-3, 4 MFMA each ----
    if (wid < 4) {
        floatx4 accd;
        float db = (llo < 5) ? dec_b[llo] : 0.f;
#pragma unroll
        for (int r = 0; r < 4; ++r) accd[r] = db;
        const ushort* bp = dec_wt + (size_t)llo * 128 + lhi * 8;
#pragma unroll
        for (int kk = 0; kk < 4; ++kk) {
            short8 bf = *(const short8*)(bp + kk * 32);
            int row = wid * 16 + llo;
            short8 a = *(const short8*)((const char*)comb + (size_t)row * 560 + kk * 64 + lhi * 16);
            accd = __builtin_amdgcn_mfma_f32_16x16x32_bf16(a, bf, accd, 0, 0, 0);
        }
        if (llo < 5) {
#pragma unroll
            for (int r = 0; r < 4; ++r) {
                int n = n0 + wid * 16 + lhi * 4 + r;
                if (n < N_NODES) out[(size_t)n * 5 + llo] = accd[r];
            }
        }
    }
}

extern "C" void kernel_launch(void* const* d_in, const int* in_sizes, int n_in,
                              void* d_out, int out_size, void* d_ws, size_t ws_size,
                              hipStream_t stream) {
    const float* x     = (const float*)d_in[0];
    const int*   ei    = (const int*)d_in[1];
    const float* ea    = (const float*)d_in[2];
    const float* enc_w = (const float*)d_in[3];
    const float* enc_b = (const float*)d_in[4];
    const float* dec_w = (const float*)d_in[5];
    const float* dec_b = (const float*)d_in[6];
    // Only layer l=3 contributes (loop overwrites h_update; h never changes).
    const float* mw1 = (const float*)d_in[7]  + (size_t)3 * 259 * HID;
    const float* mb1 = (const float*)d_in[8]  + (size_t)3 * HID;
    const float* mw2 = (const float*)d_in[9]  + (size_t)3 * HID * HID;
    const float* mb2 = (const float*)d_in[10] + (size_t)3 * HID;
    const float* uw1 = (const float*)d_in[11] + (size_t)3 * 256 * HID;
    const float* ub1 = (const float*)d_in[12] + (size_t)3 * HID;
    const float* uw2 = (const float*)d_in[13] + (size_t)3 * HID * HID;
    const float* ub2 = (const float*)d_in[14] + (size_t)3 * HID;

    char* w = (char*)d_ws;
    ushort* hb     = (ushort*)w;  w += (size_t)N_NODES * HID * 2;   // 12.8MB
    ushort* Abuf   = (ushort*)w;  w += (size_t)N_NODES * HID * 2;   // 12.8MB
    ushort* Bbuf   = (ushort*)w;  w += (size_t)N_NODES * HID * 2;   // 12.8MB
    ushort* Tb     = (ushort*)w;  w += (size_t)N_NODES * HID * 2;   // 12.8MB (bf16)
    uint*   counts = (uint*)w;    w += (size_t)50016 * 4;
    uint*   slot   = (uint*)w;    w += (size_t)N_EDGES * 4;         // 3.2MB
    uint*   rowptr = (uint*)w;    w += (size_t)50016 * 4;
    uint*   partials=(uint*)w;    w += (size_t)256 * 4;
    uint4*  epack  = (uint4*)w;   w += (size_t)N_EDGES * 16;        // 12.8MB
    ushort* w1at   = (ushort*)w;  w += (size_t)128 * 128 * 2;
    ushort* w1bt   = (ushort*)w;  w += (size_t)128 * 128 * 2;
    ushort* w2t    = (ushort*)w;  w += (size_t)128 * 128 * 2;
    ushort* uw1t   = (ushort*)w;  w += (size_t)128 * 256 * 2;
    ushort* uw2t   = (ushort*)w;  w += (size_t)128 * 128 * 2;
    ushort* dec_wt = (ushort*)w;  w += (size_t)16 * 128 * 2;
    float4* tailpack = (float4*)w; w += (size_t)128 * 16;
    float*  out    = (float*)d_out;

    hipMemsetAsync(counts, 0, (size_t)50016 * 4, stream);

    prep_hist_kernel<<<(N_EDGES + 100480 + 255) / 256, 256, 0, stream>>>(
        mw1, mb1, mw2, uw1, uw2, dec_w, w1at, w1bt, w2t, uw1t, uw2t, dec_wt,
        tailpack, ei, counts, slot);
    mega_kernel<<<PRE_B + ZERO_B + SCAN1_B, 512, 0, stream>>>(
        counts, partials, (uint4*)Tb,
        x, enc_w, enc_b, w1at, w1bt, hb, Abuf, Bbuf);
    scan3_kernel<<<SCAN_B, 256, 0, stream>>>(counts, partials, rowptr);
    build_kernel<<<(N_EDGES + 255) / 256, 256, 0, stream>>>(ei, ea, rowptr, slot, epack);
    edge_kernel<<<N_EDGES / EPB, 512, 0, stream>>>(Abuf, Bbuf, epack, tailpack, Tb);
    upd_kernel<<<(N_NODES + 63) / 64, 512, 0, stream>>>(
        hb, Tb, rowptr, w2t, mb2, ub1, ub2, uw1t, uw2t, dec_wt, dec_b, out);
}

// Round 23
// 168.774 us; speedup vs baseline: 1.0342x; 1.0342x over previous
//
#include <hip/hip_runtime.h>
#include <hip/hip_bf16.h>

#define N_NODES 50000
#define N_EDGES 800000
#define HID 128

using short8  = __attribute__((ext_vector_type(8))) short;
using floatx4 = __attribute__((ext_vector_type(4))) float;

__device__ __forceinline__ float bf2f(ushort u) {
    union { uint u32; float f; } v; v.u32 = ((uint)u) << 16; return v.f;
}
__device__ __forceinline__ ushort f2bf(float f) {
    __hip_bfloat16 b = __float2bfloat16(f);
    return *reinterpret_cast<ushort*>(&b);
}

// packed-bf16 atomic add via CAS (boundary runs only; <=3 contenders/addr)
__device__ __forceinline__ void atomicAddBf162(uint* addr, float a0, float a1) {
    uint old = *addr;
    while (true) {
        float s0 = bf2f((ushort)(old & 0xffffu)) + a0;
        float s1 = bf2f((ushort)(old >> 16)) + a1;
        uint newv = (uint)f2bf(s0) | ((uint)f2bf(s1) << 16);
        uint got = atomicCAS(addr, old, newv);
        if (got == old) break;
        old = got;
    }
}

// ---- hist (slot-returning) + prep (weight transposes), fused by gid range ----
__global__ __launch_bounds__(256) void prep_hist_kernel(
    const float* __restrict__ mw1, const float* __restrict__ mb1,
    const float* __restrict__ mw2,
    const float* __restrict__ uw1, const float* __restrict__ uw2,
    const float* __restrict__ dec_w,
    ushort* __restrict__ w1at, ushort* __restrict__ w1bt,
    ushort* __restrict__ w2t,
    ushort* __restrict__ uw1t, ushort* __restrict__ uw2t,
    ushort* __restrict__ dec_wt,
    float4* __restrict__ tailpack,
    const int* __restrict__ ei, uint* __restrict__ counts,
    uint* __restrict__ slot)
{
    int gid = blockIdx.x * 256 + threadIdx.x;
    if (gid < N_EDGES) {
        slot[gid] = atomicAdd(&counts[ei[N_EDGES + gid]], 1u);
        return;
    }
    int g0 = gid - N_EDGES;
    if (g0 < 16384) {
        int c = g0 >> 7, k = g0 & 127;
        w1at[c * 128 + k] = f2bf(mw1[(size_t)k * HID + c]);
    } else if (g0 < 32768) {
        int g = g0 - 16384, c = g >> 7, k = g & 127;
        w1bt[c * 128 + k] = f2bf(mw1[(size_t)(128 + k) * HID + c]);
    } else if (g0 < 49152) {
        int g = g0 - 32768, c = g >> 7, k = g & 127;
        w2t[c * 128 + k] = f2bf(mw2[(size_t)k * HID + c]);
    } else if (g0 < 81920) {
        int g = g0 - 49152, c = g >> 8, k = g & 255;
        uw1t[c * 256 + k] = f2bf(uw1[(size_t)k * HID + c]);
    } else if (g0 < 98304) {
        int g = g0 - 81920, c = g >> 7, k = g & 127;
        uw2t[c * 128 + k] = f2bf(uw2[(size_t)k * HID + c]);
    } else if (g0 < 98432) {
        int c = g0 - 98304;
        tailpack[c] = make_float4(mw1[(size_t)256 * HID + c],
                                  mw1[(size_t)257 * HID + c],
                                  mw1[(size_t)258 * HID + c],
                                  mb1[c]);
    } else if (g0 < 100480) {
        int g = g0 - 98432, c = g >> 7, k = g & 127;    // dec_wt [16][128], pad 0
        dec_wt[c * 128 + k] = (c < 5) ? f2bf(dec_w[(size_t)k * 5 + c]) : (ushort)0;
    }
}

// ---- mega: pre + Tb zero (bf16) + scan1, fused by block range ---------------
#define SCAN1_B 98
#define ZERO_B  1563
#define PRE_B   782
#define SCAN_B  196
__global__ __launch_bounds__(512, 2) void mega_kernel(
    const uint* __restrict__ counts, uint* __restrict__ partials,
    uint4* __restrict__ Tb4,
    const float* __restrict__ x, const float* __restrict__ enc_w,
    const float* __restrict__ enc_b,
    const ushort* __restrict__ w1at, const ushort* __restrict__ w1bt,
    ushort* __restrict__ hb, ushort* __restrict__ Abuf, ushort* __restrict__ Bbuf)
{
    __shared__ __align__(16) ushort htile[64][152];
    __shared__ __align__(16) ushort ABst[64][280];
    __shared__ float x_s[64][6];
    __shared__ float encw_s[640];
    __shared__ float encb_s[128];
    __shared__ uint sm[512];

    int tid = threadIdx.x;
    int b = blockIdx.x;

    if (b >= PRE_B) {
        if (b < PRE_B + ZERO_B) {
            int idx = (b - PRE_B) * 512 + tid;
            if (idx < 800000) Tb4[idx] = make_uint4(0, 0, 0, 0);
        } else {
            int bs = b - PRE_B - ZERO_B;   // scan1: two 256-partials per block
            int i = bs * 512 + tid;
            sm[tid] = (i < N_NODES) ? counts[i] : 0u;
            __syncthreads();
            int half = tid >> 8, t = tid & 255;
            for (int off = 128; off > 0; off >>= 1) {
                if (t < off) sm[half * 256 + t] += sm[half * 256 + t + off];
                __syncthreads();
            }
            if (t == 0) partials[2 * bs + half] = sm[half * 256];
        }
        return;
    }

    // ---- pre path ----
    int n0 = b * 64;

    if (tid < 320) {
        int nl = tid / 5, k = tid % 5;
        int n = n0 + nl;
        x_s[nl][k] = (n < N_NODES) ? x[(size_t)n * 5 + k] : 0.f;
    }
    if (tid < 128) encb_s[tid] = enc_b[tid];
    encw_s[tid] = enc_w[tid];
    if (tid < 128) encw_s[512 + tid] = enc_w[512 + tid];
    __syncthreads();

    {
        int el = tid >> 3, q = tid & 7;
        int c0 = q * 16;
        union { ushort u[16]; uint4 v[2]; } hv;
#pragma unroll
        for (int c = 0; c < 16; ++c) {
            int j = c0 + c;
            float acc = encb_s[j];
#pragma unroll
            for (int k = 0; k < 5; ++k)
                acc = fmaf(x_s[el][k], encw_s[k * 128 + j], acc);
            hv.u[c] = f2bf(acc);
        }
        *(uint4*)&htile[el][c0]     = hv.v[0];
        *(uint4*)&htile[el][c0 + 8] = hv.v[1];
        int n = n0 + el;
        if (n < N_NODES) {
            uint4* gp = (uint4*)(hb + (size_t)n * HID + c0);
            gp[0] = hv.v[0];
            gp[1] = hv.v[1];
        }
    }
    __syncthreads();

    int lane = tid & 63;
    int wid  = tid >> 6;
    int cg   = wid & 3;
    int mg   = wid >> 2;
    int lhi  = lane >> 4;
    int llo  = lane & 15;
    int col0 = cg * 32 + llo;
    int col1 = cg * 32 + 16 + llo;

    {
        floatx4 acc[2][2];
#pragma unroll
        for (int lm = 0; lm < 2; ++lm)
#pragma unroll
            for (int r = 0; r < 4; ++r) { acc[lm][0][r] = 0.f; acc[lm][1][r] = 0.f; }
        const ushort* bp0 = w1at + (size_t)col0 * 128 + lhi * 8;
        const ushort* bp1 = w1at + (size_t)col1 * 128 + lhi * 8;
#pragma unroll
        for (int kk = 0; kk < 4; ++kk) {
            short8 bf0 = *(const short8*)(bp0 + kk * 32);
            short8 bf1 = *(const short8*)(bp1 + kk * 32);
#pragma unroll
            for (int lm = 0; lm < 2; ++lm) {
                int row = (mg * 2 + lm) * 16 + llo;
                short8 a = *(const short8*)((const char*)htile + (size_t)row * 304 + kk * 64 + lhi * 16);
                acc[lm][0] = __builtin_amdgcn_mfma_f32_16x16x32_bf16(a, bf0, acc[lm][0], 0, 0, 0);
                acc[lm][1] = __builtin_amdgcn_mfma_f32_16x16x32_bf16(a, bf1, acc[lm][1], 0, 0, 0);
            }
        }
#pragma unroll
        for (int lm = 0; lm < 2; ++lm)
#pragma unroll
            for (int r = 0; r < 4; ++r) {
                int row = (mg * 2 + lm) * 16 + lhi * 4 + r;
                ABst[row][col0] = f2bf(acc[lm][0][r]);
                ABst[row][col1] = f2bf(acc[lm][1][r]);
            }
    }
    {
        floatx4 acc[2][2];
#pragma unroll
        for (int lm = 0; lm < 2; ++lm)
#pragma unroll
            for (int r = 0; r < 4; ++r) { acc[lm][0][r] = 0.f; acc[lm][1][r] = 0.f; }
        const ushort* bp0 = w1bt + (size_t)col0 * 128 + lhi * 8;
        const ushort* bp1 = w1bt + (size_t)col1 * 128 + lhi * 8;
#pragma unroll
        for (int kk = 0; kk < 4; ++kk) {
            short8 bf0 = *(const short8*)(bp0 + kk * 32);
            short8 bf1 = *(const short8*)(bp1 + kk * 32);
#pragma unroll
            for (int lm = 0; lm < 2; ++lm) {
                int row = (mg * 2 + lm) * 16 + llo;
                short8 a = *(const short8*)((const char*)htile + (size_t)row * 304 + kk * 64 + lhi * 16);
                acc[lm][0] = __builtin_amdgcn_mfma_f32_16x16x32_bf16(a, bf0, acc[lm][0], 0, 0, 0);
                acc[lm][1] = __builtin_amdgcn_mfma_f32_16x16x32_bf16(a, bf1, acc[lm][1], 0, 0, 0);
            }
        }
#pragma unroll
        for (int lm = 0; lm < 2; ++lm)
#pragma unroll
            for (int r = 0; r < 4; ++r) {
                int row = (mg * 2 + lm) * 16 + lhi * 4 + r;
                ABst[row][128 + col0] = f2bf(acc[lm][0][r]);
                ABst[row][128 + col1] = f2bf(acc[lm][1][r]);
            }
    }
    __syncthreads();

    {
        int el = tid >> 3, q = tid & 7;
        int n = n0 + el;
        if (n < N_NODES) {
            uint4* ga = (uint4*)(Abuf + (size_t)n * HID + q * 16);
            ga[0] = *(uint4*)&ABst[el][q * 16];
            ga[1] = *(uint4*)&ABst[el][q * 16 + 8];
            uint4* gb = (uint4*)(Bbuf + (size_t)n * HID + q * 16);
            gb[0] = *(uint4*)&ABst[el][128 + q * 16];
            gb[1] = *(uint4*)&ABst[el][128 + q * 16 + 8];
        }
    }
}

// scan of partials folded in: every block scans the 196 partials locally.
__global__ __launch_bounds__(256) void scan3_kernel(
    const uint* __restrict__ counts, const uint* __restrict__ partials,
    uint* __restrict__ rowptr)
{
    __shared__ uint sp[256];
    __shared__ uint sm[256];
    __shared__ uint base_s;
    int b = blockIdx.x, tid = threadIdx.x;
    uint pv = (tid < SCAN_B) ? partials[tid] : 0u;
    sp[tid] = pv;
    __syncthreads();
    for (int off = 1; off < 256; off <<= 1) {
        uint t = (tid >= off) ? sp[tid - off] : 0u;
        __syncthreads();
        sp[tid] += t;
        __syncthreads();
    }
    if (tid == (uint)b) base_s = sp[tid] - pv;   // exclusive prefix for this block
    int i = b * 256 + tid;
    uint v = (i < N_NODES) ? counts[i] : 0u;
    sm[tid] = v;
    __syncthreads();
    for (int off = 1; off < 256; off <<= 1) {
        uint t = (tid >= off) ? sm[tid - off] : 0u;
        __syncthreads();
        sm[tid] += t;
        __syncthreads();
    }
    if (i < N_NODES) rowptr[i] = sm[tid] - v + base_s;
    if (i == N_NODES - 1) rowptr[N_NODES] = N_EDGES;
}

// ---- build: scatter packed payload using precomputed slot (no atomics) ------
__global__ __launch_bounds__(256) void build_kernel(
    const int* __restrict__ ei, const float* __restrict__ ea,
    const uint* __restrict__ rowptr, const uint* __restrict__ slot,
    uint4* __restrict__ epack)
{
    int e = blockIdx.x * 256 + threadIdx.x;
    if (e >= N_EDGES) return;
    int src = ei[e];
    int dst = ei[N_EDGES + e];
    uint pos = rowptr[dst] + slot[e];
    uint4 p;
    p.x = (uint)src;
    p.y = (uint)dst;
    p.z = (uint)f2bf(ea[(size_t)e * 3 + 0]) | ((uint)f2bf(ea[(size_t)e * 3 + 1]) << 16);
    p.w = (uint)f2bf(ea[(size_t)e * 3 + 2]);
    epack[pos] = p;
}

// ---- edge: software-pipelined depth-2 + per-run base fold;
//      per-wave 40-edge window; cols {2*lane, 2*lane+1};
//      interior runs -> uint (bf16x2) store; boundaries -> CAS pk-bf16 add ----
#define EPB 320
#define EPW 40
__global__ __launch_bounds__(512) void edge_kernel(
    const ushort* __restrict__ Abuf, const ushort* __restrict__ Bbuf,
    const uint4* __restrict__ epack, const float4* __restrict__ tailpack,
    ushort* __restrict__ Tb)
{
    __shared__ __align__(16) uint4 ep_s[EPB];

    int tid = threadIdx.x;
    size_t p0 = (size_t)blockIdx.x * EPB;
    if (tid < EPB) ep_s[tid] = epack[p0 + tid];
    __syncthreads();

    int wid = tid >> 6, lane = tid & 63;
    int base = wid * EPW;
    float4 tp0 = tailpack[2 * lane];
    float4 tp1 = tailpack[2 * lane + 1];

    // pipeline prologue: payloads j=0,1 and their B-rows in flight
    uint4 pc = ep_s[base];
    uint4 pn = ep_s[base + 1];
    uint buc = ((const uint*)(Bbuf + (size_t)pc.x * HID))[lane];
    uint bun = ((const uint*)(Bbuf + (size_t)pn.x * HID))[lane];

    int prev = (int)pc.y;
    uint au = ((const uint*)(Abuf + (size_t)prev * HID))[lane];
    float base0 = tp0.w + bf2f((ushort)(au & 0xffffu));
    float base1 = tp1.w + bf2f((ushort)(au >> 16));
    float acc0 = 0.f, acc1 = 0.f;
    bool first = true;

#pragma unroll 4
    for (int j = 0; j < EPW; ++j) {
        uint4 p = pc;
        uint bu = buc;
        // advance pipeline: issue load for j+2 before any compute
        pc = pn;
        buc = bun;
        if (j + 2 < EPW) {
            pn = ep_s[base + j + 2];
            bun = ((const uint*)(Bbuf + (size_t)pn.x * HID))[lane];
        }
        int d = (int)p.y;
        if (d != prev) {                    // wave-uniform branch
            uint* Tr = (uint*)(Tb + (size_t)prev * HID) + lane;
            if (first) {
                atomicAddBf162(Tr, acc0, acc1);
            } else {
                *Tr = (uint)f2bf(acc0) | ((uint)f2bf(acc1) << 16);  // interior
            }
            first = false;
            acc0 = 0.f; acc1 = 0.f;
            prev = d;
            au = ((const uint*)(Abuf + (size_t)d * HID))[lane];
            base0 = tp0.w + bf2f((ushort)(au & 0xffffu));
            base1 = tp1.w + bf2f((ushort)(au >> 16));
        }
        float e0 = bf2f((ushort)(p.z & 0xffffu));
        float e1 = bf2f((ushort)(p.z >> 16));
        float e2 = bf2f((ushort)(p.w & 0xffffu));
        float t0 = fmaf(e0, tp0.x, fmaf(e1, tp0.y, fmaf(e2, tp0.z, base0)))
                   + bf2f((ushort)(bu & 0xffffu));
        float t1 = fmaf(e0, tp1.x, fmaf(e1, tp1.y, fmaf(e2, tp1.z, base1)))
                   + bf2f((ushort)(bu >> 16));
        acc0 += fmaxf(t0, 0.f);
        acc1 += fmaxf(t1, 0.f);
    }
    uint* Tr = (uint*)(Tb + (size_t)prev * HID) + lane;   // last run: boundary
    atomicAddBf162(Tr, acc0, acc1);
}

// ---- upd: aggr = Tb@W2 + deg*b2; node MLP + residual + MFMA decode.
__global__ __launch_bounds__(512, 6) void upd_kernel(
    const ushort* __restrict__ hb, const ushort* __restrict__ Tb,
    const uint* __restrict__ rowptr,
    const ushort* __restrict__ w2t, const float* __restrict__ mb2,
    const float* __restrict__ ub1, const float* __restrict__ ub2,
    const ushort* __restrict__ uw1t, const ushort* __restrict__ uw2t,
    const ushort* __restrict__ dec_wt, const float* __restrict__ dec_b,
    float* __restrict__ out)
{
    __shared__ __align__(16) ushort comb[64][280];   // [h | aggr] -> [hf | aggr]
    __shared__ __align__(16) ushort Tt[64][136];     // T bf16 -> t1, pitch 272B
    __shared__ float deg_s[64];

    int tid = threadIdx.x;
    int n0 = blockIdx.x * 64;

    {
        int el = tid >> 3, q = tid & 7;
        int n = n0 + el;
        if (n < N_NODES) {
            const uint4* gp = (const uint4*)(hb + (size_t)n * HID + q * 16);
            uint4* lp = (uint4*)&comb[el][q * 16];
            lp[0] = gp[0]; lp[1] = gp[1];
            const uint4* tp4 = (const uint4*)(Tb + (size_t)n * HID + q * 16);
            *(uint4*)&Tt[el][q * 16]     = tp4[0];
            *(uint4*)&Tt[el][q * 16 + 8] = tp4[1];
        } else {
            uint4 z = make_uint4(0, 0, 0, 0);
            uint4* lp = (uint4*)&comb[el][q * 16];
            lp[0] = z; lp[1] = z;
            *(uint4*)&Tt[el][q * 16]     = z;
            *(uint4*)&Tt[el][q * 16 + 8] = z;
        }
        if (tid < 64) {
            int n2 = n0 + tid;
            deg_s[tid] = (n2 < N_NODES) ? (float)(rowptr[n2 + 1] - rowptr[n2]) : 0.f;
        }
    }
    __syncthreads();

    int lane = tid & 63;
    int wid  = tid >> 6;
    int cg   = wid & 3;
    int mg   = wid >> 2;
    int lhi  = lane >> 4;
    int llo  = lane & 15;
    int col0 = cg * 32 + llo;
    int col1 = cg * 32 + 16 + llo;

    // ---- aggr = Tt @ W2 + deg*b2 -> comb[.,128:256] ----
    {
        floatx4 acc[2][2];
        float b0 = mb2[col0], b1 = mb2[col1];
#pragma unroll
        for (int lm = 0; lm < 2; ++lm)
#pragma unroll
            for (int r = 0; r < 4; ++r) {
                int row = (mg * 2 + lm) * 16 + lhi * 4 + r;
                acc[lm][0][r] = deg_s[row] * b0;
                acc[lm][1][r] = deg_s[row] * b1;
            }
        const ushort* bp0 = w2t + (size_t)col0 * 128 + lhi * 8;
        const ushort* bp1 = w2t + (size_t)col1 * 128 + lhi * 8;
#pragma unroll
        for (int kk = 0; kk < 4; ++kk) {
            short8 bf0 = *(const short8*)(bp0 + kk * 32);
            short8 bf1 = *(const short8*)(bp1 + kk * 32);
#pragma unroll
            for (int lm = 0; lm < 2; ++lm) {
                int row = (mg * 2 + lm) * 16 + llo;
                short8 a = *(const short8*)((const char*)Tt + (size_t)row * 272 + kk * 64 + lhi * 16);
                acc[lm][0] = __builtin_amdgcn_mfma_f32_16x16x32_bf16(a, bf0, acc[lm][0], 0, 0, 0);
                acc[lm][1] = __builtin_amdgcn_mfma_f32_16x16x32_bf16(a, bf1, acc[lm][1], 0, 0, 0);
            }
        }
#pragma unroll
        for (int lm = 0; lm < 2; ++lm)
#pragma unroll
            for (int r = 0; r < 4; ++r) {
                int row = (mg * 2 + lm) * 16 + lhi * 4 + r;
                comb[row][128 + col0] = f2bf(acc[lm][0][r]);
                comb[row][128 + col1] = f2bf(acc[lm][1][r]);
            }
    }
    __syncthreads();

    // ---- layer 1: comb @ uw1 + ub1, relu -> Tt (T data now dead) ----
    {
        floatx4 acc[2][2];
        float b0 = ub1[col0], b1 = ub1[col1];
#pragma unroll
        for (int lm = 0; lm < 2; ++lm)
#pragma unroll
            for (int r = 0; r < 4; ++r) { acc[lm][0][r] = b0; acc[lm][1][r] = b1; }
        const ushort* bp0 = uw1t + (size_t)col0 * 256 + lhi * 8;
        const ushort* bp1 = uw1t + (size_t)col1 * 256 + lhi * 8;
#pragma unroll
        for (int kk = 0; kk < 8; ++kk) {
            short8 bf0 = *(const short8*)(bp0 + kk * 32);
            short8 bf1 = *(const short8*)(bp1 + kk * 32);
#pragma unroll
            for (int lm = 0; lm < 2; ++lm) {
                int row = (mg * 2 + lm) * 16 + llo;
                short8 a = *(const short8*)((const char*)comb + (size_t)row * 560 + kk * 64 + lhi * 16);
                acc[lm][0] = __builtin_amdgcn_mfma_f32_16x16x32_bf16(a, bf0, acc[lm][0], 0, 0, 0);
                acc[lm][1] = __builtin_amdgcn_mfma_f32_16x16x32_bf16(a, bf1, acc[lm][1], 0, 0, 0);
            }
        }
        __syncthreads();
#pragma unroll
        for (int lm = 0; lm < 2; ++lm)
#pragma unroll
            for (int r = 0; r < 4; ++r) {
                int row = (mg * 2 + lm) * 16 + lhi * 4 + r;
                Tt[row][col0] = f2bf(fmaxf(acc[lm][0][r], 0.f));
                Tt[row][col1] = f2bf(fmaxf(acc[lm][1][r], 0.f));
            }
    }
    __syncthreads();

    // ---- layer 2 + residual -> comb[.,0:128] (hf over h, same-thread elements) -
    {
        floatx4 acc[2][2];
        float b0 = ub2[col0], b1 = ub2[col1];
#pragma unroll
        for (int lm = 0; lm < 2; ++lm)
#pragma unroll
            for (int r = 0; r < 4; ++r) { acc[lm][0][r] = b0; acc[lm][1][r] = b1; }
        const ushort* bp0 = uw2t + (size_t)col0 * 128 + lhi * 8;
        const ushort* bp1 = uw2t + (size_t)col1 * 128 + lhi * 8;
#pragma unroll
        for (int kk = 0; kk < 4; ++kk) {
            short8 bf0 = *(const short8*)(bp0 + kk * 32);
            short8 bf1 = *(const short8*)(bp1 + kk * 32);
#pragma unroll
            for (int lm = 0; lm < 2; ++lm) {
                int row = (mg * 2 + lm) * 16 + llo;
                short8 a = *(const short8*)((const char*)Tt + (size_t)row * 272 + kk * 64 + lhi * 16);
                acc[lm][0] = __builtin_amdgcn_mfma_f32_16x16x32_bf16(a, bf0, acc[lm][0], 0, 0, 0);
                acc[lm][1] = __builtin_amdgcn_mfma_f32_16x16x32_bf16(a, bf1, acc[lm][1], 0, 0, 0);
            }
        }
#pragma unroll
        for (int lm = 0; lm < 2; ++lm)
#pragma unroll
            for (int r = 0; r < 4; ++r) {
                int row = (mg * 2 + lm) * 16 + lhi * 4 + r;
                float h0 = bf2f(comb[row][col0]);
                float h1 = bf2f(comb[row][col1]);
                comb[row][col0] = f2bf(h0 + acc[lm][0][r]);
                comb[row][col1] = f2bf(h1 + acc[lm][1][r]);
            }
    }
    __syncthreads();

    // ---- decode via MFMA: [64,128] @ [128,16(pad)] ; waves 0-3, 4 MFMA each ----
    if (wid < 4) {
        floatx4 accd;
        float db = (llo < 5) ? dec_b[llo] : 0.f;
#pragma unroll
        for (int r = 0; r < 4; ++r) accd[r] = db;
        const ushort* bp = dec_wt + (size_t)llo * 128 + lhi * 8;
#pragma unroll
        for (int kk = 0; kk < 4; ++kk) {
            short8 bf = *(const short8*)(bp + kk * 32);
            int row = wid * 16 + llo;
            short8 a = *(const short8*)((const char*)comb + (size_t)row * 560 + kk * 64 + lhi * 16);
            accd = __builtin_amdgcn_mfma_f32_16x16x32_bf16(a, bf, accd, 0, 0, 0);
        }
        if (llo < 5) {
#pragma unroll
            for (int r = 0; r < 4; ++r) {
                int n = n0 + wid * 16 + lhi * 4 + r;
                if (n < N_NODES) out[(size_t)n * 5 + llo] = accd[r];
            }
        }
    }
}

extern "C" void kernel_launch(void* const* d_in, const int* in_sizes, int n_in,
                              void* d_out, int out_size, void* d_ws, size_t ws_size,
                              hipStream_t stream) {
    const float* x     = (const float*)d_in[0];
    const int*   ei    = (const int*)d_in[1];
    const float* ea    = (const float*)d_in[2];
    const float* enc_w = (const float*)d_in[3];
    const float* enc_b = (const float*)d_in[4];
    const float* dec_w = (const float*)d_in[5];
    const float* dec_b = (const float*)d_in[6];
    // Only layer l=3 contributes (loop overwrites h_update; h never changes).
    const float* mw1 = (const float*)d_in[7]  + (size_t)3 * 259 * HID;
    const float* mb1 = (const float*)d_in[8]  + (size_t)3 * HID;
    const float* mw2 = (const float*)d_in[9]  + (size_t)3 * HID * HID;
    const float* mb2 = (const float*)d_in[10] + (size_t)3 * HID;
    const float* uw1 = (const float*)d_in[11] + (size_t)3 * 256 * HID;
    const float* ub1 = (const float*)d_in[12] + (size_t)3 * HID;
    const float* uw2 = (const float*)d_in[13] + (size_t)3 * HID * HID;
    const float* ub2 = (const float*)d_in[14] + (size_t)3 * HID;

    char* w = (char*)d_ws;
    ushort* hb     = (ushort*)w;  w += (size_t)N_NODES * HID * 2;   // 12.8MB
    ushort* Abuf   = (ushort*)w;  w += (size_t)N_NODES * HID * 2;   // 12.8MB
    ushort* Bbuf   = (ushort*)w;  w += (size_t)N_NODES * HID * 2;   // 12.8MB
    ushort* Tb     = (ushort*)w;  w += (size_t)N_NODES * HID * 2;   // 12.8MB (bf16)
    uint*   counts = (uint*)w;    w += (size_t)50016 * 4;
    uint*   slot   = (uint*)w;    w += (size_t)N_EDGES * 4;         // 3.2MB
    uint*   rowptr = (uint*)w;    w += (size_t)50016 * 4;
    uint*   partials=(uint*)w;    w += (size_t)256 * 4;
    uint4*  epack  = (uint4*)w;   w += (size_t)N_EDGES * 16;        // 12.8MB
    ushort* w1at   = (ushort*)w;  w += (size_t)128 * 128 * 2;
    ushort* w1bt   = (ushort*)w;  w += (size_t)128 * 128 * 2;
    ushort* w2t    = (ushort*)w;  w += (size_t)128 * 128 * 2;
    ushort* uw1t   = (ushort*)w;  w += (size_t)128 * 256 * 2;
    ushort* uw2t   = (ushort*)w;  w += (size_t)128 * 128 * 2;
    ushort* dec_wt = (ushort*)w;  w += (size_t)16 * 128 * 2;
    float4* tailpack = (float4*)w; w += (size_t)128 * 16;
    float*  out    = (float*)d_out;

    hipMemsetAsync(counts, 0, (size_t)50016 * 4, stream);

    prep_hist_kernel<<<(N_EDGES + 100480 + 255) / 256, 256, 0, stream>>>(
        mw1, mb1, mw2, uw1, uw2, dec_w, w1at, w1bt, w2t, uw1t, uw2t, dec_wt,
        tailpack, ei, counts, slot);
    mega_kernel<<<PRE_B + ZERO_B + SCAN1_B, 512, 0, stream>>>(
        counts, partials, (uint4*)Tb,
        x, enc_w, enc_b, w1at, w1bt, hb, Abuf, Bbuf);
    scan3_kernel<<<SCAN_B, 256, 0, stream>>>(counts, partials, rowptr);
    build_kernel<<<(N_EDGES + 255) / 256, 256, 0, stream>>>(ei, ea, rowptr, slot, epack);
    edge_kernel<<<N_EDGES / EPB, 512, 0, stream>>>(Abuf, Bbuf, epack, tailpack, Tb);
    upd_kernel<<<(N_NODES + 63) / 64, 512, 0, stream>>>(
        hb, Tb, rowptr, w2t, mb2, ub1, ub2, uw1t, uw2t, dec_wt, dec_b, out);
}